// Round 4
// baseline (97.082 us; speedup 1.0000x reference)
//
#include <hip/hip_runtime.h>

#define ENT_GRID 16
#define ENT_DIM  64
#define EMB      1024   // ENT_GRID * ENT_DIM
#define LN_EPS   1e-5f

// ---------- sort-by-relation-id machinery (device-side, capture-safe) ----------

__global__ void zero_hist_kernel(int* __restrict__ hist, int n) {
    int i = blockIdx.x * blockDim.x + threadIdx.x;
    if (i < n) hist[i] = 0;
}

__global__ void hist_kernel(const int* __restrict__ ids, int* __restrict__ hist, int B) {
    int i = blockIdx.x * blockDim.x + threadIdx.x;
    if (i < B) atomicAdd(&hist[ids[i]], 1);
}

__global__ __launch_bounds__(1024)
void scan_kernel(const int* __restrict__ hist, int* __restrict__ cursor, int n) {
    const int t = threadIdx.x;
    const int ITEMS = (n + 1023) / 1024;
    int vals[8];
    int lsum = 0;
#pragma unroll
    for (int k = 0; k < 8; ++k) {
        int i = t * ITEMS + k;
        int v = (k < ITEMS && i < n) ? hist[i] : 0;
        vals[k] = v;
        lsum += v;
    }
    __shared__ int s[1024];
    s[t] = lsum;
    __syncthreads();
    for (int off = 1; off < 1024; off <<= 1) {
        int v = (t >= off) ? s[t - off] : 0;
        __syncthreads();
        s[t] += v;
        __syncthreads();
    }
    int run = s[t] - lsum;
#pragma unroll
    for (int k = 0; k < 8; ++k) {
        int i = t * ITEMS + k;
        if (k < ITEMS && i < n) cursor[i] = run;
        run += vals[k];
    }
}

__global__ void scatter_kernel(const int* __restrict__ ids, int* __restrict__ cursor,
                               int* __restrict__ perm, int B) {
    int i = blockIdx.x * blockDim.x + threadIdx.x;
    if (i < B) {
        int pos = atomicAdd(&cursor[ids[i]], 1);
        perm[pos] = i;
    }
    // after: cursor[r] == END offset of group r; start = cursor[r] - hist[r]
}

__device__ __forceinline__ float dot4(float4 a, float4 b) {
    return a.x * b.x + a.y * b.y + a.z * b.z + a.w * b.w;
}

// ---------- main kernel: one block per relation ----------
// Thread t owns outputs i = 4t..4t+3 (contiguous): tran rows 4t..4t+3 in regs
// (16 float4, loaded once), emb block d = t>>2 shared by all 4 outputs.
// Rows processed in chunks of 4: all emb loads up front, 2 barriers per chunk.
__global__ __launch_bounds__(256, 4)
void wproj_group_kernel(const float* __restrict__ ent_emb,
                        const float* __restrict__ rel_tran,
                        const float* __restrict__ rel_bias,
                        const float* __restrict__ ln_w,
                        const float* __restrict__ ln_b,
                        const int*   __restrict__ hist,
                        const int*   __restrict__ cursor_end,
                        const int*   __restrict__ perm,
                        float* __restrict__ out) {
    const int r   = blockIdx.x;
    const int cnt = hist[r];
    if (cnt == 0) return;
    const int start = cursor_end[r] - cnt;
    const int t   = threadIdx.x;
    const int wid = t >> 6;

    // 16 float4 = this thread's 4 tran rows (64 consecutive floats at t*256B)
    const float4* __restrict__ tr4 =
        reinterpret_cast<const float4*>(rel_tran + (size_t)r * (ENT_DIM * ENT_GRID * ENT_GRID))
        + (size_t)t * 16;
    float4 trv[16];
#pragma unroll
    for (int q = 0; q < 16; ++q) trv[q] = tr4[q];

    const float4 bias4 = reinterpret_cast<const float4*>(rel_bias + (size_t)r * EMB)[t];
    const float4 lw4   = reinterpret_cast<const float4*>(ln_w)[t];
    const float4 lb4   = reinterpret_cast<const float4*>(ln_b)[t];

    __shared__ float wsum[4][4], wsq[4][4];   // [row-in-chunk][wave]

    for (int base = 0; base < cnt; base += 4) {
        const int nrows = min(4, cnt - base);

        int bidx[4];
#pragma unroll
        for (int j = 0; j < 4; ++j) {
            const int jj = (j < nrows) ? j : (nrows - 1);
            bidx[j] = perm[start + base + jj];
        }

        float x[4][4];
#pragma unroll
        for (int j = 0; j < 4; ++j) {
            if (j < nrows) {
                const float4* __restrict__ e4 =
                    reinterpret_cast<const float4*>(ent_emb + (size_t)bidx[j] * EMB)
                    + (t >> 2) * 4;
                const float4 ev0 = e4[0], ev1 = e4[1], ev2 = e4[2], ev3 = e4[3];

                float s = 0.0f, ss = 0.0f;
#pragma unroll
                for (int k = 0; k < 4; ++k) {
                    float acc = (k == 0) ? bias4.x : (k == 1) ? bias4.y
                              : (k == 2) ? bias4.z : bias4.w;
                    acc += dot4(trv[k * 4 + 0], ev0);
                    acc += dot4(trv[k * 4 + 1], ev1);
                    acc += dot4(trv[k * 4 + 2], ev2);
                    acc += dot4(trv[k * 4 + 3], ev3);
                    x[j][k] = acc;
                    s  += acc;
                    ss += acc * acc;
                }
#pragma unroll
                for (int off = 32; off > 0; off >>= 1) {
                    s  += __shfl_xor(s, off, 64);
                    ss += __shfl_xor(ss, off, 64);
                }
                if ((t & 63) == 0) { wsum[j][wid] = s; wsq[j][wid] = ss; }
            }
        }
        __syncthreads();

#pragma unroll
        for (int j = 0; j < 4; ++j) {
            if (j < nrows) {
                const float tsum = wsum[j][0] + wsum[j][1] + wsum[j][2] + wsum[j][3];
                const float tsq  = wsq[j][0]  + wsq[j][1]  + wsq[j][2]  + wsq[j][3];
                const float mu   = tsum * (1.0f / (float)EMB);
                const float var  = tsq * (1.0f / (float)EMB) - mu * mu;
                const float rstd = rsqrtf(var + LN_EPS);
                float4 o;
                o.x = (x[j][0] - mu) * rstd * lw4.x + lb4.x;
                o.y = (x[j][1] - mu) * rstd * lw4.y + lb4.y;
                o.z = (x[j][2] - mu) * rstd * lw4.z + lb4.z;
                o.w = (x[j][3] - mu) * rstd * lw4.w + lb4.w;
                reinterpret_cast<float4*>(out + (size_t)bidx[j] * EMB)[t] = o;
            }
        }
        if (base + 4 < cnt) __syncthreads();   // wsum reused next chunk
    }
}

extern "C" void kernel_launch(void* const* d_in, const int* in_sizes, int n_in,
                              void* d_out, int out_size, void* d_ws, size_t ws_size,
                              hipStream_t stream) {
    const float* ent_emb  = (const float*)d_in[0];
    const int*   proj_ids = (const int*)  d_in[1];
    const float* rel_tran = (const float*)d_in[2];
    const float* rel_bias = (const float*)d_in[3];
    const float* ln_w     = (const float*)d_in[4];
    const float* ln_b     = (const float*)d_in[5];
    float* out = (float*)d_out;

    const int B  = in_sizes[1];                                     // 8192
    const int NR = in_sizes[2] / (ENT_DIM * ENT_GRID * ENT_GRID);   // 5000

    int* w      = (int*)d_ws;
    int* hist   = w;            // [NR]
    int* cursor = w + NR;       // [NR]
    int* perm   = w + 2 * NR;   // [B]

    zero_hist_kernel<<<(NR + 255) / 256, 256, 0, stream>>>(hist, NR);
    hist_kernel<<<(B + 255) / 256, 256, 0, stream>>>(proj_ids, hist, B);
    scan_kernel<<<1, 1024, 0, stream>>>(hist, cursor, NR);
    scatter_kernel<<<(B + 255) / 256, 256, 0, stream>>>(proj_ids, cursor, perm, B);

    wproj_group_kernel<<<NR, 256, 0, stream>>>(ent_emb, rel_tran, rel_bias, ln_w, ln_b,
                                               hist, cursor, perm, out);
}